// Round 1
// baseline (2288.583 us; speedup 1.0000x reference)
//
#include <hip/hip_runtime.h>
#include <stdint.h>

#define HIDDEN 4096
#define INTER  16384
#define NROWS  4096   // 2*2048 tokens

typedef __attribute__((ext_vector_type(4))) int i32x4;

__device__ __forceinline__ void gload16(const void* g, void* l) {
    __builtin_amdgcn_global_load_lds((__attribute__((address_space(1))) void*)g,
                                     (__attribute__((address_space(3))) void*)l,
                                     16, 0, 0);
}

// ---------------------------------------------------------------------------
// Per-row quantize: scale = max(absmax/7, 1e-8); q = clip(rne(x/scale),-8,7)
// Bit-exact vs reference: IEEE divide, rintf (round-half-even), exact max.
// One block (256 thr) per row; row cached in registers (single global read).
// ---------------------------------------------------------------------------
template <int COLS>
__global__ __launch_bounds__(256) void quant_rows_k(const float* __restrict__ in,
                                                    int8_t* __restrict__ q,
                                                    float* __restrict__ scales) {
    constexpr int V4 = COLS / 1024;  // float4 per thread
    const int row = blockIdx.x;
    const float4* src = (const float4*)(in + (size_t)row * COLS) + threadIdx.x;
    float4 v[V4];
    float m = 0.0f;
#pragma unroll
    for (int i = 0; i < V4; i++) {
        v[i] = src[i * 256];
        m = fmaxf(m, fmaxf(fmaxf(fabsf(v[i].x), fabsf(v[i].y)),
                           fmaxf(fabsf(v[i].z), fabsf(v[i].w))));
    }
#pragma unroll
    for (int off = 32; off > 0; off >>= 1) m = fmaxf(m, __shfl_down(m, off));
    __shared__ float red[4];
    if ((threadIdx.x & 63) == 0) red[threadIdx.x >> 6] = m;
    __syncthreads();
    m = fmaxf(fmaxf(red[0], red[1]), fmaxf(red[2], red[3]));
    const float scale = fmaxf(m / 7.0f, 1e-8f);
    if (threadIdx.x == 0) scales[row] = scale;
    char4* dst = (char4*)(q + (size_t)row * COLS) + threadIdx.x;
#pragma unroll
    for (int i = 0; i < V4; i++) {
        char4 o;
        o.x = (signed char)fminf(fmaxf(rintf(v[i].x / scale), -8.0f), 7.0f);
        o.y = (signed char)fminf(fmaxf(rintf(v[i].y / scale), -8.0f), 7.0f);
        o.z = (signed char)fminf(fmaxf(rintf(v[i].z / scale), -8.0f), 7.0f);
        o.w = (signed char)fminf(fmaxf(rintf(v[i].w / scale), -8.0f), 7.0f);
        dst[i * 256] = o;
    }
}

// ---------------------------------------------------------------------------
// GEMM1 (+ dequant + SiLU*up fused): h[m, c] for a 128(M) x 64(col-pair) tile.
// B-tile rows 0..63 = gate cols [n0,n0+64), rows 64..127 = up cols (same c),
// so gate/up for a column live in the SAME wave -> no epilogue exchange.
// Wave w handles rows [w*32, w*32+32): acc[2 m-frag][8 n-frag] int32.
// ---------------------------------------------------------------------------
__global__ __launch_bounds__(256) void gemm1_silu(const int8_t* __restrict__ xq,
                                                  const float* __restrict__ sx,
                                                  const int8_t* __restrict__ wq,
                                                  const float* __restrict__ sgu,
                                                  float* __restrict__ h) {
    __shared__ int8_t lsA[128 * 64];
    __shared__ int8_t lsB[128 * 64];
    const int t = threadIdx.x;
    const int lane = t & 63;
    const int w = t >> 6;
    const int m0 = blockIdx.x * 128;  // m-tile fastest: concurrent blocks share B-slab
    const int n0 = blockIdx.y * 64;

    const int8_t* ga0 = xq + (size_t)(m0 + (t >> 2)) * HIDDEN + (t & 3) * 16;
    const int8_t* ga1 = ga0 + (size_t)64 * HIDDEN;
    const int8_t* gb0 = wq + (size_t)(n0 + (t >> 2)) * HIDDEN + (t & 3) * 16;
    const int8_t* gb1 = wq + (size_t)(INTER + n0 + (t >> 2)) * HIDDEN + (t & 3) * 16;
    int8_t* la0 = lsA + t * 16;
    int8_t* la1 = lsA + (t + 256) * 16;
    int8_t* lb0 = lsB + t * 16;
    int8_t* lb1 = lsB + (t + 256) * 16;

    i32x4 acc[2][8];
#pragma unroll
    for (int i = 0; i < 2; i++)
#pragma unroll
        for (int j = 0; j < 8; j++) acc[i][j] = i32x4{0, 0, 0, 0};

    const int koff = (lane >> 4) * 16;
    const int8_t* fA0 = lsA + (w * 32 + (lane & 15)) * 64 + koff;
    const int8_t* fB0 = lsB + (lane & 15) * 64 + koff;

    for (int k0 = 0; k0 < HIDDEN; k0 += 64) {
        gload16(ga0 + k0, la0);
        gload16(ga1 + k0, la1);
        gload16(gb0 + k0, lb0);
        gload16(gb1 + k0, lb1);
        __syncthreads();  // drains vmcnt (global_load_lds) + joins
        i32x4 a0 = *(const i32x4*)(fA0);
        i32x4 a1 = *(const i32x4*)(fA0 + 16 * 64);
#pragma unroll
        for (int nt = 0; nt < 8; nt++) {
            i32x4 b = *(const i32x4*)(fB0 + nt * 16 * 64);
            acc[0][nt] = __builtin_amdgcn_mfma_i32_16x16x64_i8(a0, b, acc[0][nt], 0, 0, 0);
            acc[1][nt] = __builtin_amdgcn_mfma_i32_16x16x64_i8(a1, b, acc[1][nt], 0, 0, 0);
        }
        __syncthreads();  // protect LDS before next iteration's staging
    }

    const int quad = lane >> 4;
#pragma unroll
    for (int mt = 0; mt < 2; mt++) {
#pragma unroll
        for (int nt = 0; nt < 4; nt++) {
            const int colg = n0 + nt * 16 + (lane & 15);
            const float sg = sgu[colg];
            const float su = sgu[INTER + colg];
#pragma unroll
            for (int r = 0; r < 4; r++) {
                const int row = m0 + w * 32 + mt * 16 + quad * 4 + r;
                const float sxv = sx[row];
                const float g = (float)acc[mt][nt][r] * (sxv * sg);
                const float u = (float)acc[mt][nt + 4][r] * (sxv * su);
                const float hv = g / (1.0f + expf(-g)) * u;  // jax.nn.silu
                h[(size_t)row * INTER + colg] = hv;
            }
        }
    }
}

// ---------------------------------------------------------------------------
// FWHT(16384) + had_scale + requantize. One block per row. 16384 = 128r x 128c.
// Phase 1 (regs): c-strides 1..32 + stride 64 via shfl_xor(1)  (global 1..64)
// Phase 2 (regs): r-strides 1..32 + stride 64 via shfl_xor(1)  (global 128..8192)
// Identical butterfly tree to the reference => bit-exact in fp32.
// LDS transpose uses +4r rotation swizzle (write b128 ~8-way, read b32 2-way free).
// ---------------------------------------------------------------------------
__global__ __launch_bounds__(256) void fwht_quant(const float* __restrict__ h,
                                                  int8_t* __restrict__ hq,
                                                  float* __restrict__ sh) {
    __shared__ float buf[16384];  // 64 KB
    const int t = threadIdx.x;
    const int row = blockIdx.x;
    float v[64];

    {   // load: r = t>>1, c-half = t&1
        const float4* src = (const float4*)(h + (size_t)row * INTER + (t >> 1) * 128 + (t & 1) * 64);
#pragma unroll
        for (int j = 0; j < 16; j++) {
            float4 x = src[j];
            v[4 * j] = x.x; v[4 * j + 1] = x.y; v[4 * j + 2] = x.z; v[4 * j + 3] = x.w;
        }
    }
#pragma unroll
    for (int ls = 0; ls < 6; ls++) {  // c-strides 1..32
        const int s = 1 << ls;
#pragma unroll
        for (int i = 0; i < 64; i++)
            if ((i & s) == 0) { float a = v[i], b = v[i | s]; v[i] = a + b; v[i | s] = a - b; }
    }
#pragma unroll
    for (int j = 0; j < 64; j++) {    // c-stride 64: partner lane t^1
        float o = __shfl_xor(v[j], 1, 64);
        v[j] = (t & 1) ? (o - v[j]) : (v[j] + o);
    }
    {   // swizzled LDS write: phys = r*128 + ((c + 4r) & 127)
        const int r = t >> 1, c0 = (t & 1) * 64;
        float* base = buf + r * 128;
#pragma unroll
        for (int j = 0; j < 16; j++) {
            const int c = (c0 + 4 * j + 4 * r) & 127;
            *(float4*)(base + c) = make_float4(v[4 * j], v[4 * j + 1], v[4 * j + 2], v[4 * j + 3]);
        }
    }
    __syncthreads();
    {   // phase-2 gather: c = t>>1, r = (t&1)*64 + j  (2-way banks: free)
        const int c = t >> 1, r0 = (t & 1) * 64;
#pragma unroll
        for (int j = 0; j < 64; j++) {
            const int r = r0 + j;
            v[j] = buf[r * 128 + ((c + 4 * r) & 127)];
        }
    }
    __syncthreads();  // buf reads complete before reuse below
#pragma unroll
    for (int ls = 0; ls < 6; ls++) {  // r-strides 1..32 (global 128..4096)
        const int s = 1 << ls;
#pragma unroll
        for (int i = 0; i < 64; i++)
            if ((i & s) == 0) { float a = v[i], b = v[i | s]; v[i] = a + b; v[i | s] = a - b; }
    }
#pragma unroll
    for (int j = 0; j < 64; j++) {    // r-stride 64 (global 8192): partner t^1
        float o = __shfl_xor(v[j], 1, 64);
        v[j] = (t & 1) ? (o - v[j]) : (v[j] + o);
    }
    float m = 0.0f;
#pragma unroll
    for (int j = 0; j < 64; j++) {    // had_scale = 1/128 (exact pow2)
        v[j] *= 0.0078125f;
        m = fmaxf(m, fabsf(v[j]));
    }
#pragma unroll
    for (int off = 32; off > 0; off >>= 1) m = fmaxf(m, __shfl_down(m, off));
    if ((t & 63) == 0) buf[t >> 6] = m;
    __syncthreads();
    m = fmaxf(fmaxf(buf[0], buf[1]), fmaxf(buf[2], buf[3]));
    const float scale = fmaxf(m / 7.0f, 1e-8f);
    if (t == 0) sh[row] = scale;
    int8_t* dst = hq + (size_t)row * INTER + (t >> 1);
    const int r0 = (t & 1) * 64;
#pragma unroll
    for (int j = 0; j < 64; j++) {
        float q = fminf(fmaxf(rintf(v[j] / scale), -8.0f), 7.0f);
        dst[(size_t)(r0 + j) * 128] = (int8_t)q;
    }
}

// ---------------------------------------------------------------------------
// GEMM2: out(4096x4096) = hq(4096x16384) @ wdq(4096x16384)^T, dequant epilogue.
// 128x128 tile, 4 waves in 2x2 grid, each 64x64 (4x4 MFMA frags).
// ---------------------------------------------------------------------------
__global__ __launch_bounds__(256) void gemm2_kernel(const int8_t* __restrict__ hq,
                                                    const float* __restrict__ sh,
                                                    const int8_t* __restrict__ wdq,
                                                    const float* __restrict__ sd,
                                                    float* __restrict__ out) {
    __shared__ int8_t lsA[128 * 64];
    __shared__ int8_t lsB[128 * 64];
    const int t = threadIdx.x;
    const int lane = t & 63;
    const int w = t >> 6;
    const int wm = w & 1, wn = w >> 1;
    const int m0 = blockIdx.x * 128;
    const int n0 = blockIdx.y * 128;

    const int8_t* ga0 = hq + (size_t)(m0 + (t >> 2)) * INTER + (t & 3) * 16;
    const int8_t* ga1 = ga0 + (size_t)64 * INTER;
    const int8_t* gb0 = wdq + (size_t)(n0 + (t >> 2)) * INTER + (t & 3) * 16;
    const int8_t* gb1 = gb0 + (size_t)64 * INTER;
    int8_t* la0 = lsA + t * 16;
    int8_t* la1 = lsA + (t + 256) * 16;
    int8_t* lb0 = lsB + t * 16;
    int8_t* lb1 = lsB + (t + 256) * 16;

    i32x4 acc[4][4];
#pragma unroll
    for (int i = 0; i < 4; i++)
#pragma unroll
        for (int j = 0; j < 4; j++) acc[i][j] = i32x4{0, 0, 0, 0};

    const int koff = (lane >> 4) * 16;
    const int8_t* fA = lsA + (wm * 64 + (lane & 15)) * 64 + koff;
    const int8_t* fB = lsB + (wn * 64 + (lane & 15)) * 64 + koff;

    for (int k0 = 0; k0 < INTER; k0 += 64) {
        gload16(ga0 + k0, la0);
        gload16(ga1 + k0, la1);
        gload16(gb0 + k0, lb0);
        gload16(gb1 + k0, lb1);
        __syncthreads();
        i32x4 a[4], b[4];
#pragma unroll
        for (int i = 0; i < 4; i++) {
            a[i] = *(const i32x4*)(fA + i * 16 * 64);
            b[i] = *(const i32x4*)(fB + i * 16 * 64);
        }
#pragma unroll
        for (int mt = 0; mt < 4; mt++)
#pragma unroll
            for (int nt = 0; nt < 4; nt++)
                acc[mt][nt] = __builtin_amdgcn_mfma_i32_16x16x64_i8(a[mt], b[nt], acc[mt][nt], 0, 0, 0);
        __syncthreads();
    }

    const int quad = lane >> 4;
#pragma unroll
    for (int mt = 0; mt < 4; mt++) {
#pragma unroll
        for (int nt = 0; nt < 4; nt++) {
            const int col = n0 + wn * 64 + nt * 16 + (lane & 15);
            const float sdv = sd[col];
#pragma unroll
            for (int r = 0; r < 4; r++) {
                const int row = m0 + wm * 64 + mt * 16 + quad * 4 + r;
                out[(size_t)row * HIDDEN + col] = (float)acc[mt][nt][r] * (sh[row] * sdv);
            }
        }
    }
}

// ---------------------------------------------------------------------------
extern "C" void kernel_launch(void* const* d_in, const int* in_sizes, int n_in,
                              void* d_out, int out_size, void* d_ws, size_t ws_size,
                              hipStream_t stream) {
    const float* x   = (const float*)d_in[0];  // (2,2048,4096)
    const float* wgu = (const float*)d_in[1];  // (32768,4096)
    const float* wd  = (const float*)d_in[2];  // (4096,16384)
    float* out = (float*)d_out;

    uint8_t* ws = (uint8_t*)d_ws;
    // workspace layout (all 256B-aligned)
    int8_t* xq  = (int8_t*)(ws);                                   // 16 MB
    int8_t* wq  = (int8_t*)(ws + 16777216);                        // 128 MB
    int8_t* wdq = (int8_t*)(ws + 150994944);                       // 64 MB
    int8_t* hq  = (int8_t*)(ws + 218103808);                       // 64 MB
    float*  h   = (float*)(ws + 285212672);                        // 256 MB
    float*  sx  = (float*)(ws + 553648128);                        // 16 KB
    float*  sgu = (float*)(ws + 553648128 + 16384);                // 128 KB
    float*  sd  = (float*)(ws + 553648128 + 16384 + 131072);       // 16 KB
    float*  sh  = (float*)(ws + 553648128 + 16384 + 131072 + 16384);

    quant_rows_k<HIDDEN><<<NROWS, 256, 0, stream>>>(x, xq, sx);
    quant_rows_k<HIDDEN><<<2 * INTER, 256, 0, stream>>>(wgu, wq, sgu);
    quant_rows_k<INTER><<<HIDDEN, 256, 0, stream>>>(wd, wdq, sd);
    gemm1_silu<<<dim3(NROWS / 128, INTER / 64), 256, 0, stream>>>(xq, sx, wq, sgu, h);
    fwht_quant<<<NROWS, 256, 0, stream>>>(h, hq, sh);
    gemm2_kernel<<<dim3(NROWS / 128, HIDDEN / 128), 256, 0, stream>>>(hq, sh, wdq, sd, out);
}